// Round 17
// baseline (179.760 us; speedup 1.0000x reference)
//
#include <hip/hip_runtime.h>
#include <hip/hip_bf16.h>

typedef __attribute__((ext_vector_type(8))) short short8;
typedef __attribute__((ext_vector_type(4))) float f32x4;
typedef __attribute__((ext_vector_type(2))) unsigned int u32x2;

#define E_DIM 300
#define NCH   128
#define NOUT  384      // 3 grams * 128 channels
#define NCHUNK 30      // K = 960 = 30 chunks of 32

#define OPITCH 792     // out-tile row pitch bytes

__device__ __forceinline__ unsigned short f2bf(float f) {
    unsigned int u = __float_as_uint(f);
    u += 0x7FFFu + ((u >> 16) & 1u);          // RNE
    return (unsigned short)(u >> 16);
}

// XCD-colocating bijection for grid 1152 = 128 b x 9 p.  (validated R8: -4us)
__device__ __forceinline__ void xcd_map(int bx, int& b, int& p) {
    int x = bx & 7;
    int j = bx >> 3;        // 0..143
    b = x * 16 + j / 9;
    p = j - (j / 9) * 9;
}

// ---- fused pack: conv weights -> Wp  AND  emb -> bf16 (one dispatch) --------
// blocks [0,1440): Wp[chunk=30][n=384][ke=32]; blocks [1440,6128): embh rows
// padded to 320 (640B). Fusion overlaps the two independent streams and saves
// one launch gap (~3-4us).
__global__ void pack_all(const float* __restrict__ w1, const float* __restrict__ w2,
                         const float* __restrict__ w3, const float* __restrict__ emb,
                         unsigned short* __restrict__ Wp, unsigned short* __restrict__ embh) {
    int bx = blockIdx.x;
    if (bx < 1440) {
        int idx = bx * 256 + threadIdx.x;
        if (idx >= NCHUNK * NOUT * 32) return;
        int ke = idx & 31;
        int n  = (idx >> 5) % NOUT;
        int c  = idx / (32 * NOUT);
        int s  = c / 10;
        int e  = (c % 10) * 32 + ke;
        int g  = n >> 7, o = n & 127, h = g + 1;
        float v = 0.0f;
        if (e < E_DIM && s < h) {
            const float* w = (g == 0) ? w1 : ((g == 1) ? w2 : w3);
            v = w[(o * E_DIM + e) * h + s];
        }
        Wp[idx] = f2bf(v);
    } else {
        int u = (bx - 1440) * 256 + threadIdx.x;  // 30000*40 units of 8 cols
        if (u >= 30000 * 40) return;
        int row = u / 40;
        int c8  = u - row * 40;
        int col = c8 * 8;
        ushort4 lo = {0, 0, 0, 0}, hi = {0, 0, 0, 0};
        const float* src = emb + (size_t)row * E_DIM + col;
        if (col + 8 <= E_DIM) {
            float4 a = *(const float4*)src;
            float4 c = *(const float4*)(src + 4);
            lo.x = f2bf(a.x); lo.y = f2bf(a.y); lo.z = f2bf(a.z); lo.w = f2bf(a.w);
            hi.x = f2bf(c.x); hi.y = f2bf(c.y); hi.z = f2bf(c.z); hi.w = f2bf(c.w);
        } else if (col < E_DIM) {                // col==296: 4 valid, 4 pad
            float4 a = *(const float4*)src;
            lo.x = f2bf(a.x); lo.y = f2bf(a.y); lo.z = f2bf(a.z); lo.w = f2bf(a.w);
        }
        unsigned short* dst = embh + (size_t)row * 320 + col;
        *(ushort4*)dst       = lo;
        *(ushort4*)(dst + 4) = hi;
    }
}

// ---- gather + 3 convs as one MFMA GEMM ---------------------------------------
// R13 M=64 structure (measured optimum). Depth-2 B prefetch (R16 depth-3 was
// null). 8 waves x (M=64, N=48). Shift-phase K loop, XOR-swizzled A tile,
// bf16 gather, shared inv-norm, LDS-staged output, NT stores.
__launch_bounds__(512, 4)
__global__ void conv_mfma(const int* __restrict__ tokens_q, const int* __restrict__ tokens_d,
                          const unsigned short* __restrict__ embh, const unsigned short* __restrict__ Wp,
                          const float* __restrict__ b1, const float* __restrict__ b2,
                          const float* __restrict__ b3,
                          unsigned short* __restrict__ hq, unsigned short* __restrict__ hd) {
    // union: A-tile 66 rows x 640B = 42240B  /  out-tile 64 rows x 792B = 50688B
    __shared__ __align__(16) char lds[64 * OPITCH];
    __shared__ float nrm[64 * 3];

    int b, tile;
    xcd_map(blockIdx.x, b, tile);
    int isq  = (tile == 0);
    int L    = isq ? 64 : 512;
    int t0   = isq ? 0 : (tile - 1) * 64;
    const int* toks = isq ? (tokens_q + b * 64) : (tokens_d + b * 512);
    int tid  = threadIdx.x;
    int lane = tid & 63;
    int wn   = tid >> 6;          // 8 waves; wave wn owns cols g*128 + wn*16 + lr
    int lr   = lane & 15;
    int lg   = lane >> 4;

    if (tid < 192) nrm[tid] = 0.0f;

    // depth-2 B preload (chunks 0,1) issued BEFORE gather
    const unsigned short* __restrict__ wpB = Wp + (size_t)(wn * 16 + lr) * 32 + lg * 8;
    short8 bb[2][3];
    #pragma unroll
    for (int g = 0; g < 3; ++g) {
        bb[0][g] = *(const short8*)(wpB + (size_t)(0 * NOUT + g * 128) * 32);
        bb[1][g] = *(const short8*)(wpB + (size_t)(1 * NOUT + g * 128) * 32);
    }

    // ---- bf16 gather: 8 threads/row, 16B units u = sl + 8k (k=0..4).
    // XOR swizzle: 16B unit u of row r lands at byte (u*16) ^ ((r&7)<<4).
    {
        auto gather_row = [&](int r, int sl) {
            int pos = t0 + r;
            int tk  = (pos < L) ? toks[pos] : -1;
            char* wbase = lds + r * 640;
            int xr = (r & 7) << 4;
            if (tk >= 0) {
                const unsigned short* src = embh + (size_t)tk * 320 + sl * 8;
                uint4 v[5];
                #pragma unroll
                for (int k = 0; k < 5; ++k) v[k] = *(const uint4*)(src + k * 64);
                #pragma unroll
                for (int k = 0; k < 5; ++k)
                    *(uint4*)(wbase + (((sl + 8 * k) * 16) ^ xr)) = v[k];
            } else {
                uint4 z = {0, 0, 0, 0};
                #pragma unroll
                for (int k = 0; k < 5; ++k)
                    *(uint4*)(wbase + (((sl + 8 * k) * 16) ^ xr)) = z;
            }
        };
        gather_row(tid >> 3, tid & 7);
        if (tid < 16) gather_row(64 + (tid >> 3), tid & 7);
    }
    __syncthreads();

    f32x4 acc[4][3];
    #pragma unroll
    for (int i = 0; i < 4; ++i)
        #pragma unroll
        for (int g = 0; g < 3; ++g) acc[i][g] = (f32x4){0.f, 0.f, 0.f, 0.f};

    #pragma unroll
    for (int c = 0; c < NCHUNK; ++c) {
        const int S  = (c >= 20) ? 2 : ((c >= 10) ? 1 : 0);
        const int ec = c - S * 10;
        short8 a[4];
        #pragma unroll
        for (int i = 0; i < 4; ++i) {
            int row = i * 16 + lr + S;
            int byt = (ec * 64 + lg * 16) ^ ((row & 7) << 4);
            a[i] = *(const short8*)(lds + row * 640 + byt);
        }
        #pragma unroll
        for (int i = 0; i < 4; ++i)
            #pragma unroll
            for (int g = S; g < 3; ++g)
                acc[i][g] = __builtin_amdgcn_mfma_f32_16x16x32_bf16(a[i], bb[c & 1][g], acc[i][g], 0, 0, 0);
        if (c < NCHUNK - 2) {
            const int S2 = ((c + 2) >= 20) ? 2 : (((c + 2) >= 10) ? 1 : 0);
            #pragma unroll
            for (int g = S2; g < 3; ++g)
                bb[c & 1][g] = *(const short8*)(wpB + (size_t)((c + 2) * NOUT + g * 128) * 32);
        }
    }

    // bias + relu + per-row sum of squares (16-lane xor reduce)
    #pragma unroll
    for (int g = 0; g < 3; ++g) {
        float bv = (g == 0 ? b1 : (g == 1 ? b2 : b3))[wn * 16 + lr];
        #pragma unroll
        for (int i = 0; i < 4; ++i)
            #pragma unroll
            for (int r = 0; r < 4; ++r) {
                float v = acc[i][g][r] + bv;
                v = v > 0.0f ? v : 0.0f;
                acc[i][g][r] = v;
                float s = v * v;
                s += __shfl_xor(s, 1, 16);
                s += __shfl_xor(s, 2, 16);
                s += __shfl_xor(s, 4, 16);
                s += __shfl_xor(s, 8, 16);
                if (lr == 0) atomicAdd(&nrm[(i * 16 + lg * 4 + r) * 3 + g], s);
            }
    }
    __syncthreads();   // all K-loops + atomics done; A region reusable

    // shared inverse norm: 192 values computed ONCE
    if (tid < 192) nrm[tid] = 1.0f / (sqrtf(nrm[tid]) + 1e-13f);
    __syncthreads();

    // normalize in-register, stage bf16 to LDS out-tile
    unsigned short* os = (unsigned short*)lds;
    #pragma unroll
    for (int i = 0; i < 4; ++i)
        #pragma unroll
        for (int r = 0; r < 4; ++r) {
            int row = i * 16 + lg * 4 + r;
            #pragma unroll
            for (int g = 0; g < 3; ++g)
                os[row * (OPITCH / 2) + g * 128 + wn * 16 + lr] = f2bf(acc[i][g][r] * nrm[row * 3 + g]);
        }
    __syncthreads();

    // coalesced copy-out: 8B per lane, 256B-contiguous global segments.
    // NON-TEMPORAL: do not allocate in L2/L3 (protects emb_bf residency).
    unsigned short* outp = isq ? hq : hd;
    #pragma unroll
    for (int it = 0; it < 12; ++it) {
        int idx = it * 512 + tid;            // 64 rows * 96 x 8B
        int row = idx / 96;
        int c8  = idx - row * 96;            // 8B = 4 ch
        int g   = c8 >> 5;
        int ch  = (c8 & 31) * 4;
        u32x2 v = *(const u32x2*)(lds + row * OPITCH + c8 * 8);
        __builtin_nontemporal_store(v, (u32x2*)&outp[((size_t)(g * 128 + b) * L + t0 + row) * NCH + ch]);
    }
}

// ---- MFMA cosine + RBF + log-pool -------------------------------------------
// R17: NO d-staging, NO in-loop barriers. sim's MFMA is 4% (9.7 GFLOP ~ 4us);
// the LDS stage + 8 per-chunk vmcnt(0)-drain barriers served a nearly-free
// matrix phase. a-fragments read DIRECT from dsrc: per-instruction the wave
// covers 16 rows x 64B = 1KB coalesced; d-tile is L2-resident (XCD-colocated
// 3x reuse) and the intra-block 4-wave reuse moves to L1 (16KB/chunk working
// set). Live set ~50 regs (qk[11]+qf[4]+addr), no barrier-crossing state ->
// no spill surface. R15 algebraic B-chain retained. Body numerics identical.
__launch_bounds__(256, 2)
__global__ void sim_rbf(const unsigned short* __restrict__ hq,
                        const unsigned short* __restrict__ hd,
                        const int* __restrict__ tokens_q, const int* __restrict__ tokens_d,
                        float* __restrict__ cross) {
    __shared__ unsigned char dm_s[512];
    __shared__ float logk_s[11];

    int b, p;
    xcd_map(blockIdx.x, b, p);
    int gq = p / 3;
    int gd = p % 3;
    int tid = threadIdx.x;
    int lane = tid & 63;
    int wn   = tid >> 6;      // wave -> q n-tile
    int lr   = lane & 15;
    int lg   = lane >> 4;

    if (tid < 11) logk_s[tid] = 0.0f;
    for (int i = tid; i < 512; i += 256)
        dm_s[i] = (tokens_d[b * 512 + i] > 0) ? 1 : 0;

    const unsigned short* qsrc = hq + ((size_t)(gq * 128 + b) * 64) * NCH;
    const unsigned short* dsrc = hd + ((size_t)(gd * 128 + b) * 512) * NCH;

    int q  = wn * 16 + lr;
    float qm = (tokens_q[b * 64 + q] > 0) ? 1.0f : 0.0f;

    short8 qf[4];
    #pragma unroll
    for (int ks = 0; ks < 4; ++ks)
        qf[ks] = *(const short8*)&qsrc[q * NCH + ks * 32 + lg * 8];

    __syncthreads();   // dm_s ready (the only barrier before the epilogue)

    float qk[11];
    #pragma unroll
    for (int k = 0; k < 11; ++k) qk[k] = 0.0f;

    const float C4 = 0.0183156389f;   // e^-4

    for (int ch = 0; ch < 8; ++ch) {
        #pragma unroll
        for (int mt = 0; mt < 4; ++mt) {
            const unsigned short* dr = dsrc + ((size_t)(ch * 64 + mt * 16 + lr)) * NCH + lg * 8;
            f32x4 acc = (f32x4){0.f, 0.f, 0.f, 0.f};
            #pragma unroll
            for (int ks = 0; ks < 4; ++ks) {
                short8 a = *(const short8*)(dr + ks * 32);
                acc = __builtin_amdgcn_mfma_f32_16x16x32_bf16(a, qf[ks], acc, 0, 0, 0);
            }
            uchar4 du = *(const uchar4*)&dm_s[ch * 64 + mt * 16 + lg * 4];
            float cv[4], cm[4];
            cm[0] = qm * (float)du.x; cm[1] = qm * (float)du.y;
            cm[2] = qm * (float)du.z; cm[3] = qm * (float)du.w;
            #pragma unroll
            for (int r2 = 0; r2 < 4; ++r2) cv[r2] = acc[r2] * cm[r2];

            // exact-match kernel (sigma=0.001): c <= 0.98 terms are fp32 zero
            float cmx = fmaxf(fmaxf(cv[0], cv[1]), fmaxf(cv[2], cv[3]));
            if (__any(cmx > 0.98f)) {
                #pragma unroll
                for (int r2 = 0; r2 < 4; ++r2) {
                    if (cv[r2] > 0.98f) {
                        float t0 = cv[r2] - 1.0f;
                        qk[0] += __expf(-500000.0f * t0 * t0);
                    }
                }
            }
            // k=1..10: chain A (2 exps); chain B derived algebraically:
            // TB = TA*exp(-20c), exp(-20c) = e^-4*rcp(UA), UB = e^-4*that.
            #pragma unroll
            for (int r2 = 0; r2 < 4; ++r2) {
                float c  = cv[r2];
                float tA = c - 0.1f;
                float TA = __expf(-50.0f * tA * tA) * cm[r2];
                float UA = __expf(20.0f * c - 4.0f);
                float s  = C4 * __builtin_amdgcn_rcpf(UA);   // = exp(-20c)
                float TB = TA * s;                            // masked via TA
                float UB = C4 * s;                            // = exp(-20c-4)
                qk[5] += TA;
                TA *= UA; qk[4] += TA; UA *= C4;
                TA *= UA; qk[3] += TA; UA *= C4;
                TA *= UA; qk[2] += TA; UA *= C4;
                TA *= UA; qk[1] += TA;
                qk[6] += TB;
                TB *= UB; qk[7] += TB; UB *= C4;
                TB *= UB; qk[8] += TB; UB *= C4;
                TB *= UB; qk[9] += TB; UB *= C4;
                TB *= UB; qk[10] += TB;
            }
        }
    }

    #pragma unroll
    for (int k = 0; k < 11; ++k) {
        float v = qk[k];
        v += __shfl_xor(v, 16);
        v += __shfl_xor(v, 32);
        qk[k] = v;
    }
    if (lg == 0) {
        #pragma unroll
        for (int k = 0; k < 11; ++k) {
            float lv = __logf(fmaxf(qk[k], 1e-10f)) * 0.01f;
            atomicAdd(&logk_s[k], lv);
        }
    }
    __syncthreads();
    if (tid < 11) cross[b * 99 + p * 11 + tid] = logk_s[tid];
}

// ---------------- final FC ----------------
__global__ void fc_kernel(const float* __restrict__ cross, const float* __restrict__ fc_w,
                          const float* __restrict__ fc_b, float* __restrict__ out) {
    int b = threadIdx.x;   // 128
    float acc = fc_b[0];
    #pragma unroll 11
    for (int j = 0; j < 99; ++j) acc += cross[b * 99 + j] * fc_w[j];
    out[b] = acc;
}

extern "C" void kernel_launch(void* const* d_in, const int* in_sizes, int n_in,
                              void* d_out, int out_size, void* d_ws, size_t ws_size,
                              hipStream_t stream) {
    const int*   tq  = (const int*)d_in[0];
    const int*   td  = (const int*)d_in[1];
    const float* emb = (const float*)d_in[2];
    const float* w1  = (const float*)d_in[3];
    const float* cb1 = (const float*)d_in[4];
    const float* w2  = (const float*)d_in[5];
    const float* cb2 = (const float*)d_in[6];
    const float* w3  = (const float*)d_in[7];
    const float* cb3 = (const float*)d_in[8];
    const float* fcw = (const float*)d_in[9];
    const float* fcb = (const float*)d_in[10];

    char* ws = (char*)d_ws;
    unsigned short* Wp    = (unsigned short*)ws;             // 737280 B
    float*          cross = (float*)(ws + 921600);
    unsigned short* hq    = (unsigned short*)(ws + 1048576); // 6291456 B
    unsigned short* hd    = (unsigned short*)(ws + 8388608); // 50331648 B
    unsigned short* embh  = (unsigned short*)(ws + 58720256);// 19200000 B (total ~78MB)

    hipLaunchKernelGGL(pack_all, dim3(6128), dim3(256), 0, stream, w1, w2, w3, emb, Wp, embh);
    hipLaunchKernelGGL(conv_mfma, dim3(128 * 9), dim3(512), 0, stream,
                       tq, td, embh, Wp, cb1, cb2, cb3, hq, hd);
    hipLaunchKernelGGL(sim_rbf, dim3(128 * 9), dim3(256), 0, stream, hq, hd, tq, td, cross);
    hipLaunchKernelGGL(fc_kernel, dim3(1), dim3(128), 0, stream, cross, fcw, fcb, (float*)d_out);
}

// Round 18
// 165.675 us; speedup vs baseline: 1.0850x; 1.0850x over previous
//
#include <hip/hip_runtime.h>
#include <hip/hip_bf16.h>

typedef __attribute__((ext_vector_type(8))) short short8;
typedef __attribute__((ext_vector_type(4))) float f32x4;
typedef __attribute__((ext_vector_type(2))) unsigned int u32x2;

#define E_DIM 300
#define NCH   128
#define NOUT  384      // 3 grams * 128 channels
#define NCHUNK 30      // K = 960 = 30 chunks of 32

#define OPITCH 792     // out-tile row pitch bytes

// async global->LDS, 16B per lane; LDS dest = wave-uniform base + lane*16
#define GLD16(gp, lp) __builtin_amdgcn_global_load_lds( \
    (const __attribute__((address_space(1))) unsigned int*)(const void*)(gp), \
    (__attribute__((address_space(3))) unsigned int*)(void*)(lp), 16, 0, 0)

__device__ __forceinline__ unsigned short f2bf(float f) {
    unsigned int u = __float_as_uint(f);
    u += 0x7FFFu + ((u >> 16) & 1u);          // RNE
    return (unsigned short)(u >> 16);
}

// XCD-colocating bijection for grid 1152 = 128 b x 9 p.  (validated R8: -4us)
__device__ __forceinline__ void xcd_map(int bx, int& b, int& p) {
    int x = bx & 7;
    int j = bx >> 3;        // 0..143
    b = x * 16 + j / 9;
    p = j - (j / 9) * 9;
}

// ---- fused pack: conv weights -> Wp  AND  emb -> bf16 (one dispatch) --------
__global__ void pack_all(const float* __restrict__ w1, const float* __restrict__ w2,
                         const float* __restrict__ w3, const float* __restrict__ emb,
                         unsigned short* __restrict__ Wp, unsigned short* __restrict__ embh) {
    int bx = blockIdx.x;
    if (bx < 1440) {
        int idx = bx * 256 + threadIdx.x;
        if (idx >= NCHUNK * NOUT * 32) return;
        int ke = idx & 31;
        int n  = (idx >> 5) % NOUT;
        int c  = idx / (32 * NOUT);
        int s  = c / 10;
        int e  = (c % 10) * 32 + ke;
        int g  = n >> 7, o = n & 127, h = g + 1;
        float v = 0.0f;
        if (e < E_DIM && s < h) {
            const float* w = (g == 0) ? w1 : ((g == 1) ? w2 : w3);
            v = w[(o * E_DIM + e) * h + s];
        }
        Wp[idx] = f2bf(v);
    } else {
        int u = (bx - 1440) * 256 + threadIdx.x;  // 30000*40 units of 8 cols
        if (u >= 30000 * 40) return;
        int row = u / 40;
        int c8  = u - row * 40;
        int col = c8 * 8;
        ushort4 lo = {0, 0, 0, 0}, hi = {0, 0, 0, 0};
        const float* src = emb + (size_t)row * E_DIM + col;
        if (col + 8 <= E_DIM) {
            float4 a = *(const float4*)src;
            float4 c = *(const float4*)(src + 4);
            lo.x = f2bf(a.x); lo.y = f2bf(a.y); lo.z = f2bf(a.z); lo.w = f2bf(a.w);
            hi.x = f2bf(c.x); hi.y = f2bf(c.y); hi.z = f2bf(c.z); hi.w = f2bf(c.w);
        } else if (col < E_DIM) {                // col==296: 4 valid, 4 pad
            float4 a = *(const float4*)src;
            lo.x = f2bf(a.x); lo.y = f2bf(a.y); lo.z = f2bf(a.z); lo.w = f2bf(a.w);
        }
        unsigned short* dst = embh + (size_t)row * 320 + col;
        *(ushort4*)dst       = lo;
        *(ushort4*)(dst + 4) = hi;
    }
}

// ---- gather + 3 convs as one MFMA GEMM ---------------------------------------
// R13 M=64 structure (measured optimum). Depth-2 B prefetch. 8 waves x
// (M=64, N=48). Shift-phase K loop, XOR-swizzled A tile, bf16 gather,
// shared inv-norm, LDS-staged output, NT stores.
__launch_bounds__(512, 4)
__global__ void conv_mfma(const int* __restrict__ tokens_q, const int* __restrict__ tokens_d,
                          const unsigned short* __restrict__ embh, const unsigned short* __restrict__ Wp,
                          const float* __restrict__ b1, const float* __restrict__ b2,
                          const float* __restrict__ b3,
                          unsigned short* __restrict__ hq, unsigned short* __restrict__ hd) {
    // union: A-tile 66 rows x 640B = 42240B  /  out-tile 64 rows x 792B = 50688B
    __shared__ __align__(16) char lds[64 * OPITCH];
    __shared__ float nrm[64 * 3];

    int b, tile;
    xcd_map(blockIdx.x, b, tile);
    int isq  = (tile == 0);
    int L    = isq ? 64 : 512;
    int t0   = isq ? 0 : (tile - 1) * 64;
    const int* toks = isq ? (tokens_q + b * 64) : (tokens_d + b * 512);
    int tid  = threadIdx.x;
    int lane = tid & 63;
    int wn   = tid >> 6;          // 8 waves; wave wn owns cols g*128 + wn*16 + lr
    int lr   = lane & 15;
    int lg   = lane >> 4;

    if (tid < 192) nrm[tid] = 0.0f;

    // depth-2 B preload (chunks 0,1) issued BEFORE gather
    const unsigned short* __restrict__ wpB = Wp + (size_t)(wn * 16 + lr) * 32 + lg * 8;
    short8 bb[2][3];
    #pragma unroll
    for (int g = 0; g < 3; ++g) {
        bb[0][g] = *(const short8*)(wpB + (size_t)(0 * NOUT + g * 128) * 32);
        bb[1][g] = *(const short8*)(wpB + (size_t)(1 * NOUT + g * 128) * 32);
    }

    // ---- bf16 gather: 8 threads/row, 16B units u = sl + 8k (k=0..4).
    // XOR swizzle: 16B unit u of row r lands at byte (u*16) ^ ((r&7)<<4).
    {
        auto gather_row = [&](int r, int sl) {
            int pos = t0 + r;
            int tk  = (pos < L) ? toks[pos] : -1;
            char* wbase = lds + r * 640;
            int xr = (r & 7) << 4;
            if (tk >= 0) {
                const unsigned short* src = embh + (size_t)tk * 320 + sl * 8;
                uint4 v[5];
                #pragma unroll
                for (int k = 0; k < 5; ++k) v[k] = *(const uint4*)(src + k * 64);
                #pragma unroll
                for (int k = 0; k < 5; ++k)
                    *(uint4*)(wbase + (((sl + 8 * k) * 16) ^ xr)) = v[k];
            } else {
                uint4 z = {0, 0, 0, 0};
                #pragma unroll
                for (int k = 0; k < 5; ++k)
                    *(uint4*)(wbase + (((sl + 8 * k) * 16) ^ xr)) = z;
            }
        };
        gather_row(tid >> 3, tid & 7);
        if (tid < 16) gather_row(64 + (tid >> 3), tid & 7);
    }
    __syncthreads();

    f32x4 acc[4][3];
    #pragma unroll
    for (int i = 0; i < 4; ++i)
        #pragma unroll
        for (int g = 0; g < 3; ++g) acc[i][g] = (f32x4){0.f, 0.f, 0.f, 0.f};

    #pragma unroll
    for (int c = 0; c < NCHUNK; ++c) {
        const int S  = (c >= 20) ? 2 : ((c >= 10) ? 1 : 0);
        const int ec = c - S * 10;
        short8 a[4];
        #pragma unroll
        for (int i = 0; i < 4; ++i) {
            int row = i * 16 + lr + S;
            int byt = (ec * 64 + lg * 16) ^ ((row & 7) << 4);
            a[i] = *(const short8*)(lds + row * 640 + byt);
        }
        #pragma unroll
        for (int i = 0; i < 4; ++i)
            #pragma unroll
            for (int g = S; g < 3; ++g)
                acc[i][g] = __builtin_amdgcn_mfma_f32_16x16x32_bf16(a[i], bb[c & 1][g], acc[i][g], 0, 0, 0);
        if (c < NCHUNK - 2) {
            const int S2 = ((c + 2) >= 20) ? 2 : (((c + 2) >= 10) ? 1 : 0);
            #pragma unroll
            for (int g = S2; g < 3; ++g)
                bb[c & 1][g] = *(const short8*)(wpB + (size_t)((c + 2) * NOUT + g * 128) * 32);
        }
    }

    // bias + relu + per-row sum of squares (16-lane xor reduce)
    #pragma unroll
    for (int g = 0; g < 3; ++g) {
        float bv = (g == 0 ? b1 : (g == 1 ? b2 : b3))[wn * 16 + lr];
        #pragma unroll
        for (int i = 0; i < 4; ++i)
            #pragma unroll
            for (int r = 0; r < 4; ++r) {
                float v = acc[i][g][r] + bv;
                v = v > 0.0f ? v : 0.0f;
                acc[i][g][r] = v;
                float s = v * v;
                s += __shfl_xor(s, 1, 16);
                s += __shfl_xor(s, 2, 16);
                s += __shfl_xor(s, 4, 16);
                s += __shfl_xor(s, 8, 16);
                if (lr == 0) atomicAdd(&nrm[(i * 16 + lg * 4 + r) * 3 + g], s);
            }
    }
    __syncthreads();   // all K-loops + atomics done; A region reusable

    // shared inverse norm: 192 values computed ONCE
    if (tid < 192) nrm[tid] = 1.0f / (sqrtf(nrm[tid]) + 1e-13f);
    __syncthreads();

    // normalize in-register, stage bf16 to LDS out-tile
    unsigned short* os = (unsigned short*)lds;
    #pragma unroll
    for (int i = 0; i < 4; ++i)
        #pragma unroll
        for (int r = 0; r < 4; ++r) {
            int row = i * 16 + lg * 4 + r;
            #pragma unroll
            for (int g = 0; g < 3; ++g)
                os[row * (OPITCH / 2) + g * 128 + wn * 16 + lr] = f2bf(acc[i][g][r] * nrm[row * 3 + g]);
        }
    __syncthreads();

    // coalesced copy-out: 8B per lane, 256B-contiguous global segments.
    // NON-TEMPORAL: do not allocate in L2/L3 (protects emb_bf residency).
    unsigned short* outp = isq ? hq : hd;
    #pragma unroll
    for (int it = 0; it < 12; ++it) {
        int idx = it * 512 + tid;            // 64 rows * 96 x 8B
        int row = idx / 96;
        int c8  = idx - row * 96;            // 8B = 4 ch
        int g   = c8 >> 5;
        int ch  = (c8 & 31) * 4;
        u32x2 v = *(const u32x2*)(lds + row * OPITCH + c8 * 8);
        __builtin_nontemporal_store(v, (u32x2*)&outp[((size_t)(g * 128 + b) * L + t0 + row) * NCH + ch]);
    }
}

// ---- MFMA cosine + RBF + log-pool -------------------------------------------
// R16 sim body VERBATIM (measured ~65us): GLD16 double-buffered d-staging
// (linear LDS, source-swizzled), qf reloaded per chunk, R15 algebraic B-chain.
// R17 lesson: removing the staging exposed per-mt VMEM latency (65->94us) —
// the async chunk-ahead pipeline earns its barriers.
__launch_bounds__(256, 2)
__global__ void sim_rbf(const unsigned short* __restrict__ hq,
                        const unsigned short* __restrict__ hd,
                        const int* __restrict__ tokens_q, const int* __restrict__ tokens_d,
                        float* __restrict__ cross) {
    __shared__ __align__(16) short ds2[2][64 * 128];   // 32768 B, linear rows
    __shared__ unsigned char dm_s[512];
    __shared__ float logk_s[11];

    int b, p;
    xcd_map(blockIdx.x, b, p);
    int gq = p / 3;
    int gd = p % 3;
    int tid = threadIdx.x;
    int lane = tid & 63;
    int wn   = tid >> 6;      // wave -> q n-tile AND staging row group
    int lr   = lane & 15;
    int lg   = lane >> 4;

    if (tid < 11) logk_s[tid] = 0.0f;

    const unsigned short* qsrc = hq + ((size_t)(gq * 128 + b) * 64) * NCH;
    const unsigned short* dsrc = hd + ((size_t)(gd * 128 + b) * 512) * NCH;

    int q  = wn * 16 + lr;
    float qm = (tokens_q[b * 64 + q] > 0) ? 1.0f : 0.0f;

    int rloc = 4 * wn + (lane >> 4);              // row within it-group
    int cu   = (lane & 15) ^ (rloc & 7);          // pre-swizzled global col unit

    auto stage = [&](int bufI, int ch) {
        const unsigned short* s0 = dsrc + ((size_t)ch * 64 + rloc) * NCH + cu * 8;
        #pragma unroll
        for (int it = 0; it < 4; ++it)
            GLD16(s0 + (size_t)it * 16 * NCH, &ds2[bufI][(it * 16 + 4 * wn) * 128]);
    };

    stage(0, 0);
    for (int i = tid; i < 512; i += 256)
        dm_s[i] = (tokens_d[b * 512 + i] > 0) ? 1 : 0;
    __syncthreads();   // drains vmcnt -> buffer 0 ready

    float qk[11];
    #pragma unroll
    for (int k = 0; k < 11; ++k) qk[k] = 0.0f;

    const float C4 = 0.0183156389f;   // e^-4

    for (int ch = 0; ch < 8; ++ch) {
        int buf = ch & 1;
        if (ch < 7) stage(buf ^ 1, ch + 1);   // async; hides under compute below

        short8 qf[4];
        #pragma unroll
        for (int ks = 0; ks < 4; ++ks)
            qf[ks] = *(const short8*)&qsrc[q * NCH + ks * 32 + lg * 8];

        #pragma unroll
        for (int mt = 0; mt < 4; ++mt) {
            int r = mt * 16 + lr;
            f32x4 acc = (f32x4){0.f, 0.f, 0.f, 0.f};
            #pragma unroll
            for (int ks = 0; ks < 4; ++ks) {
                short8 a = *(const short8*)((const char*)&ds2[buf][0]
                              + r * 256 + (((ks * 4 + lg) ^ (r & 7)) << 4));
                acc = __builtin_amdgcn_mfma_f32_16x16x32_bf16(a, qf[ks], acc, 0, 0, 0);
            }
            uchar4 du = *(const uchar4*)&dm_s[ch * 64 + mt * 16 + lg * 4];
            float cv[4], cm[4];
            cm[0] = qm * (float)du.x; cm[1] = qm * (float)du.y;
            cm[2] = qm * (float)du.z; cm[3] = qm * (float)du.w;
            #pragma unroll
            for (int r2 = 0; r2 < 4; ++r2) cv[r2] = acc[r2] * cm[r2];

            // exact-match kernel (sigma=0.001): c <= 0.98 terms are fp32 zero
            float cmx = fmaxf(fmaxf(cv[0], cv[1]), fmaxf(cv[2], cv[3]));
            if (__any(cmx > 0.98f)) {
                #pragma unroll
                for (int r2 = 0; r2 < 4; ++r2) {
                    if (cv[r2] > 0.98f) {
                        float t0 = cv[r2] - 1.0f;
                        qk[0] += __expf(-500000.0f * t0 * t0);
                    }
                }
            }
            // k=1..10: chain A (2 exps); chain B derived algebraically:
            // TB = TA*exp(-20c), exp(-20c) = e^-4*rcp(UA), UB = e^-4*that.
            #pragma unroll
            for (int r2 = 0; r2 < 4; ++r2) {
                float c  = cv[r2];
                float tA = c - 0.1f;
                float TA = __expf(-50.0f * tA * tA) * cm[r2];
                float UA = __expf(20.0f * c - 4.0f);
                float s  = C4 * __builtin_amdgcn_rcpf(UA);   // = exp(-20c)
                float TB = TA * s;                            // masked via TA
                float UB = C4 * s;                            // = exp(-20c-4)
                qk[5] += TA;
                TA *= UA; qk[4] += TA; UA *= C4;
                TA *= UA; qk[3] += TA; UA *= C4;
                TA *= UA; qk[2] += TA; UA *= C4;
                TA *= UA; qk[1] += TA;
                qk[6] += TB;
                TB *= UB; qk[7] += TB; UB *= C4;
                TB *= UB; qk[8] += TB; UB *= C4;
                TB *= UB; qk[9] += TB; UB *= C4;
                TB *= UB; qk[10] += TB;
            }
        }

        __syncthreads();   // drains stage's vmcnt + all ds reads of buf
    }

    #pragma unroll
    for (int k = 0; k < 11; ++k) {
        float v = qk[k];
        v += __shfl_xor(v, 16);
        v += __shfl_xor(v, 32);
        qk[k] = v;
    }
    if (lg == 0) {
        #pragma unroll
        for (int k = 0; k < 11; ++k) {
            float lv = __logf(fmaxf(qk[k], 1e-10f)) * 0.01f;
            atomicAdd(&logk_s[k], lv);
        }
    }
    __syncthreads();
    if (tid < 11) cross[b * 99 + p * 11 + tid] = logk_s[tid];
}

// ---------------- final FC ----------------
__global__ void fc_kernel(const float* __restrict__ cross, const float* __restrict__ fc_w,
                          const float* __restrict__ fc_b, float* __restrict__ out) {
    int b = threadIdx.x;   // 128
    float acc = fc_b[0];
    #pragma unroll 11
    for (int j = 0; j < 99; ++j) acc += cross[b * 99 + j] * fc_w[j];
    out[b] = acc;
}

extern "C" void kernel_launch(void* const* d_in, const int* in_sizes, int n_in,
                              void* d_out, int out_size, void* d_ws, size_t ws_size,
                              hipStream_t stream) {
    const int*   tq  = (const int*)d_in[0];
    const int*   td  = (const int*)d_in[1];
    const float* emb = (const float*)d_in[2];
    const float* w1  = (const float*)d_in[3];
    const float* cb1 = (const float*)d_in[4];
    const float* w2  = (const float*)d_in[5];
    const float* cb2 = (const float*)d_in[6];
    const float* w3  = (const float*)d_in[7];
    const float* cb3 = (const float*)d_in[8];
    const float* fcw = (const float*)d_in[9];
    const float* fcb = (const float*)d_in[10];

    char* ws = (char*)d_ws;
    unsigned short* Wp    = (unsigned short*)ws;             // 737280 B
    float*          cross = (float*)(ws + 921600);
    unsigned short* hq    = (unsigned short*)(ws + 1048576); // 6291456 B
    unsigned short* hd    = (unsigned short*)(ws + 8388608); // 50331648 B
    unsigned short* embh  = (unsigned short*)(ws + 58720256);// 19200000 B (total ~78MB)

    hipLaunchKernelGGL(pack_all, dim3(6128), dim3(256), 0, stream, w1, w2, w3, emb, Wp, embh);
    hipLaunchKernelGGL(conv_mfma, dim3(128 * 9), dim3(512), 0, stream,
                       tq, td, embh, Wp, cb1, cb2, cb3, hq, hd);
    hipLaunchKernelGGL(sim_rbf, dim3(128 * 9), dim3(256), 0, stream, hq, hd, tq, td, cross);
    hipLaunchKernelGGL(fc_kernel, dim3(1), dim3(128), 0, stream, cross, fcw, fcb, (float*)d_out);
}